// Round 1
// baseline (947.433 us; speedup 1.0000x reference)
//
#include <hip/hip_runtime.h>
#include <stdint.h>

static constexpr int BB = 8;
static constexpr int SS = 4096;
static constexpr int HH = 1024;

// ---- monotonic float<->uint mapping (order-preserving, for atomicMax) ----
__device__ __forceinline__ unsigned f2mono(float f) {
    unsigned u = __float_as_uint(f);
    return (u & 0x80000000u) ? ~u : (u | 0x80000000u);
}
__device__ __forceinline__ float mono2f(unsigned u) {
    return __uint_as_float((u & 0x80000000u) ? (u ^ 0x80000000u) : ~u);
}

// ---- kernel 0: amin over attention_mask, bmax over bias ----
__global__ void reduce_ab(const float* __restrict__ a, const float* __restrict__ bias,
                          float* __restrict__ amin_out, float* __restrict__ bmax_out) {
    __shared__ float red[256];
    int t = threadIdx.x;
    float mn = 1e30f;
    for (int i = t; i < BB * SS; i += 256) mn = fminf(mn, a[i]);
    red[t] = mn; __syncthreads();
    for (int o = 128; o; o >>= 1) { if (t < o) red[t] = fminf(red[t], red[t + o]); __syncthreads(); }
    if (t == 0) *amin_out = red[0];
    __syncthreads();
    float mx = -1e30f;
    for (int i = t; i < HH; i += 256) mx = fmaxf(mx, bias[i]);
    red[t] = mx; __syncthreads();
    for (int o = 128; o; o >>= 1) { if (t < o) red[t] = fmaxf(red[t], red[t + o]); __syncthreads(); }
    if (t == 0) *bmax_out = red[0];
}

// ---- kernel A: per-batch-row compaction (one 64-lane wave per row) ----
__global__ void compact(const float* __restrict__ prev, const float* __restrict__ a,
                        int* __restrict__ kept_src, unsigned* __restrict__ scores,
                        int* __restrict__ n_keep, int* __restrict__ zcnt) {
    int b = blockIdx.x;
    int lane = threadIdx.x;          // 0..63, one wave
    const float* pm = prev + (size_t)b * SS;
    const float* am = a + (size_t)b * SS;
    int* ks = kept_src + (size_t)b * SS;

    int base_s = lane * (SS / 64);   // 64 contiguous elements per lane
    int cnt = 0, zc = 0;
    for (int i = 0; i < SS / 64; ++i) {
        if (pm[base_s + i] > 0.5f) {
            cnt++;
            if (am[base_s + i] == 0.0f) zc++;
        }
    }
    // inclusive scan of cnt across the wave
    int incl = cnt;
    for (int o = 1; o < 64; o <<= 1) {
        int v = __shfl_up(incl, o);
        if (lane >= o) incl += v;
    }
    int total = __shfl(incl, 63);
    int pos = incl - cnt;            // exclusive prefix
    for (int i = 0; i < SS / 64; ++i) {
        if (pm[base_s + i] > 0.5f) ks[pos++] = base_s + i;
    }
    for (int o = 1; o < 64; o <<= 1) zc += __shfl_xor(zc, o);
    if (lane == 0) { n_keep[b] = total; zcnt[b] = zc; }
    // pad remaining sources with row 0 (safe dummy), zero the score buffer
    for (int j = total + lane; j < SS; j += 64) ks[j] = 0;
    unsigned* sc = scores + (size_t)b * SS;
    for (int j = lane; j < SS; j += 64) sc[j] = 0u;
}

// ---- kernel B: gathered GEMM + bias + max-over-columns -> atomicMax(score) ----
// tile: 32 rows x 256 cols, 256 threads (4 waves), per-thread 8x4 register tile.
#define MT 32
#define NT 256
__global__ __launch_bounds__(256) void gemm_max(
    const float* __restrict__ hs, const float* __restrict__ W,
    const float* __restrict__ bias, const int* __restrict__ kept_src,
    const int* __restrict__ n_keep, unsigned* __restrict__ scores) {
    int mt = blockIdx.x;   // 0..127
    int nt = blockIdx.y;   // 0..3
    int b  = blockIdx.z;   // 0..7
    int nk = n_keep[b];
    int m0 = mt * MT;
    if (m0 >= nk) return;

    __shared__ float A[32][MT];      // [k within chunk][m]
    __shared__ int src[MT];
    int t  = threadIdx.x;
    int tn = t & 63;                 // lane within wave -> 4 columns
    int tm = t >> 6;                 // wave id -> 8 rows
    if (t < MT) src[t] = kept_src[(size_t)b * SS + m0 + t];
    __syncthreads();

    float acc[32];
#pragma unroll
    for (int i = 0; i < 32; ++i) acc[i] = 0.f;

    int n0 = nt * NT;
    const float* wp = W + n0 + tn * 4;
    int sm = t >> 3;                 // staging row 0..31
    int kq = t & 7;                  // staging k-quad 0..7
    const float* myrow = hs + ((size_t)b * SS + (size_t)src[sm]) * HH + kq * 4;

    for (int kc = 0; kc < HH / 32; ++kc) {
        float4 f = *(const float4*)(myrow + kc * 32);
        A[kq * 4 + 0][sm] = f.x; A[kq * 4 + 1][sm] = f.y;
        A[kq * 4 + 2][sm] = f.z; A[kq * 4 + 3][sm] = f.w;
        __syncthreads();
        const float* wk = wp + (size_t)kc * 32 * HH;
#pragma unroll 4
        for (int k = 0; k < 32; ++k) {
            float4 w4 = *(const float4*)wk;
            wk += HH;
            const float4* ar = (const float4*)(&A[k][tm * 8]);   // broadcast reads
            float4 a0 = ar[0], a1 = ar[1];
            float av[8] = {a0.x, a0.y, a0.z, a0.w, a1.x, a1.y, a1.z, a1.w};
            float wv[4] = {w4.x, w4.y, w4.z, w4.w};
#pragma unroll
            for (int i = 0; i < 8; ++i)
#pragma unroll
                for (int c = 0; c < 4; ++c)
                    acc[i * 4 + c] = fmaf(av[i], wv[c], acc[i * 4 + c]);
        }
        __syncthreads();
    }

    float4 bia = *(const float4*)(bias + n0 + tn * 4);
    float bv[4] = {bia.x, bia.y, bia.z, bia.w};
#pragma unroll
    for (int i = 0; i < 8; ++i) {
        float v = -1e30f;
#pragma unroll
        for (int c = 0; c < 4; ++c) v = fmaxf(v, acc[i * 4 + c] + bv[c]);
        for (int o = 32; o; o >>= 1) v = fmaxf(v, __shfl_xor(v, o));
        if (tn == 0)
            atomicMax(scores + (size_t)b * SS + m0 + tm * 8 + i, f2mono(v));
    }
}

// ---- kernel C: per-row stable top-k (bitonic sort) + scatter ----
__global__ __launch_bounds__(1024) void topk_scatter(
    const float* __restrict__ a, const float* __restrict__ prev,
    const int* __restrict__ kept_src, const unsigned* __restrict__ scores,
    const int* __restrict__ n_keep, const int* __restrict__ zcnt,
    const float* __restrict__ amin_p, const float* __restrict__ bmax_p,
    float* __restrict__ out_mask) {
    __shared__ unsigned long long keys[SS];   // 32 KiB
    int b = blockIdx.x;
    int t = threadIdx.x;
    int nk = n_keep[b];
    float amin = *amin_p, bmax = *bmax_p;
    int z = zcnt[b] + ((amin == 0.0f) ? (SS - nk) : 0);
    int tk = (int)((float)z * 0.8f);          // replicate f32 mul + trunc cast
    if (tk < 1) tk = 1;
    float padv = (bmax + amin * 100.0f) + amin;

    const int* ks = kept_src + (size_t)b * SS;
    const unsigned* sc = scores + (size_t)b * SS;
    const float* arow = a + (size_t)b * SS;

    for (int j = t; j < SS; j += 1024) {
        float sval;
        if (j < nk) {
            float core = mono2f(sc[j]);
            float av = arow[ks[j]];
            sval = (core + av * 100.0f) + av;  // replicate reference op order
        } else {
            sval = padv;
        }
        // ascending sort on (~mono(val), j)  ==  value desc, index asc (stable)
        keys[j] = ((unsigned long long)(~f2mono(sval)) << 32) | (unsigned)j;
    }
    // initialize output row with previous_mask
    float* om = out_mask + (size_t)b * SS;
    const float* pm = prev + (size_t)b * SS;
    for (int j = t; j < SS; j += 1024) om[j] = pm[j];
    __syncthreads();

    // bitonic sort, ascending
    for (int k = 2; k <= SS; k <<= 1) {
        for (int jj = k >> 1; jj > 0; jj >>= 1) {
            for (int i = t; i < SS; i += 1024) {
                int ixj = i ^ jj;
                if (ixj > i) {
                    bool up = ((i & k) == 0);
                    unsigned long long x = keys[i], y = keys[ixj];
                    if ((x > y) == up) { keys[i] = y; keys[ixj] = x; }
                }
            }
            __syncthreads();
        }
    }

    for (int p = t; p < SS; p += 1024) {
        int j = (int)(keys[p] & 0xFFFFFFFFull);
        if (j < nk) om[ks[j]] = (p < tk) ? 1.0f : 0.0f;
    }
}

extern "C" void kernel_launch(void* const* d_in, const int* in_sizes, int n_in,
                              void* d_out, int out_size, void* d_ws, size_t ws_size,
                              hipStream_t stream) {
    const float* hs   = (const float*)d_in[0];   // [8,4096,1024]
    const float* am   = (const float*)d_in[1];   // [8,4096]
    const float* pmsk = (const float*)d_in[2];   // [8,4096]
    const float* W    = (const float*)d_in[3];   // [1024,1024]
    const float* bias = (const float*)d_in[4];   // [1024]

    float* out0 = (float*)d_out;                       // new_ret
    float* out1 = out0 + (size_t)BB * SS * HH;         // new_mask

    char* ws = (char*)d_ws;
    int*      kept_src = (int*)ws;                                // 128 KiB
    unsigned* scores   = (unsigned*)(ws + (size_t)BB * SS * 4);   // 128 KiB
    int*      nkeep    = (int*)(ws + (size_t)2 * BB * SS * 4);
    int*      zc       = nkeep + BB;
    float*    amin_p   = (float*)(zc + BB);
    float*    bmax_p   = amin_p + 1;

    // output 0: new_ret == hidden_states exactly
    hipMemcpyAsync(out0, hs, (size_t)BB * SS * HH * sizeof(float),
                   hipMemcpyDeviceToDevice, stream);

    hipLaunchKernelGGL(reduce_ab, dim3(1), dim3(256), 0, stream, am, bias, amin_p, bmax_p);
    hipLaunchKernelGGL(compact, dim3(BB), dim3(64), 0, stream,
                       pmsk, am, kept_src, scores, nkeep, zc);
    hipLaunchKernelGGL(gemm_max, dim3(SS / MT, HH / NT, BB), dim3(256), 0, stream,
                       hs, W, bias, kept_src, nkeep, scores);
    hipLaunchKernelGGL(topk_scatter, dim3(BB), dim3(1024), 0, stream,
                       am, pmsk, kept_src, scores, nkeep, zc, amin_p, bmax_p, out1);
}